// Round 15
// baseline (267.587 us; speedup 1.0000x reference)
//
#include <hip/hip_runtime.h>

typedef unsigned short u16t;
typedef __bf16  bf8   __attribute__((ext_vector_type(8)));
typedef float   f32x4 __attribute__((ext_vector_type(4)));
typedef unsigned short us4 __attribute__((ext_vector_type(4)));

#define DEV __device__ __forceinline__

DEV float bf2f(u16t u) { union { unsigned u; float f; } x; x.u = ((unsigned)u) << 16; return x.f; }
DEV u16t  f2bf(float f) {
    union { float f; unsigned u; } x; x.f = f;
    unsigned r = x.u + 0x7FFFu + ((x.u >> 16) & 1u);
    return (u16t)(r >> 16);
}
DEV uint4 pack8(const float* v) {
    uint4 r;
    r.x = (unsigned)f2bf(v[0]) | ((unsigned)f2bf(v[1]) << 16);
    r.y = (unsigned)f2bf(v[2]) | ((unsigned)f2bf(v[3]) << 16);
    r.z = (unsigned)f2bf(v[4]) | ((unsigned)f2bf(v[5]) << 16);
    r.w = (unsigned)f2bf(v[6]) | ((unsigned)f2bf(v[7]) << 16);
    return r;
}
// async global->LDS, 16B per lane; lds dest = wave-uniform base + lane*16
DEV void gll16(const void* g, void* l) {
    __builtin_amdgcn_global_load_lds(
        (const __attribute__((address_space(1))) unsigned*)g,
        (__attribute__((address_space(3))) unsigned*)l, 16, 0, 0);
}

#define DMODEL 512
#define SEQ    1024
#define NBATCH 8

// -------------------------- ws-too-small sentinel --------------------------
__global__ __launch_bounds__(256) void fill_sentinel(float* out, int n)
{
    int i = blockIdx.x * 256 + threadIdx.x;
    if (i < n) out[i] = 100.f;
}

// -------------------------- fused prologue ---------------------------------
// R13 (kept — saved ~9us): cvt3 + transpose6 + colmean in ONE launch; the
// transpose/colmean work runs concurrently under cvt3's stream.
// grid (2048, 4): y<3 = cvt q/k/v; y==3: x<1536 transpose6, x<1792 colmean.
__global__ __launch_bounds__(256) void prep(
    const float* q, const float* k, const float* v,
    u16t* Qb, u16t* Kb, u16t* Vb,
    const float* s0, const float* s1, const float* s2, const float* s3,
    const float* s4, const float* s5,
    u16t* d0, u16t* d1, u16t* d2, u16t* d3, u16t* d4, u16t* d5,
    float* prof)
{
    __shared__ u16t tile[32][33];
    int y = blockIdx.y, tid = threadIdx.x;
    if (y < 3) {
        const float* s = (y == 0) ? q : (y == 1) ? k : v;
        u16t*        d = (y == 0) ? Qb : (y == 1) ? Kb : Vb;
        size_t i = ((size_t)blockIdx.x * 256 + tid) * 8;
        float4 a = *(const float4*)(s + i), b = *(const float4*)(s + i + 4);
        float o[8] = {a.x, a.y, a.z, a.w, b.x, b.y, b.z, b.w};
        *(uint4*)&d[i] = pack8(o);
        return;
    }
    int x = blockIdx.x;
    if (x < 1536) {                       // ---- transpose6 ----
        int z = x >> 8, rem = x & 255;
        int bx = rem & 15, by = rem >> 4;
        const float* S; u16t* D; int R, C;
        switch (z) {
            case 0: S = s0; D = d0; R = 512; C = 512; break;
            case 1: S = s1; D = d1; R = 512; C = 512; break;
            case 2: S = s2; D = d2; R = 512; C = 512; break;
            case 3: S = s3; D = d3; R = 512; C = 512; break;
            case 4: S = s4; D = d4; R = 512; C = 256; break;  // Ws1 [512,256]
            default:S = s5; D = d5; R = 256; C = 512; break;  // Ws2 [256,512]
        }
        int c0 = bx * 32, r0 = by * 32;
        if (c0 >= C || r0 >= R) return;
        int tx = tid & 31, ty = tid >> 5;   // 32 x 8
#pragma unroll
        for (int p = 0; p < 4; ++p) {
            int r = ty + p * 8;
            tile[r][tx] = f2bf(S[(size_t)(r0 + r) * C + c0 + tx]);
        }
        __syncthreads();
#pragma unroll
        for (int p = 0; p < 4; ++p) {
            int r = ty + p * 8;
            D[(size_t)(c0 + r) * R + r0 + tx] = tile[tx][r];
        }
    } else if (x < 1792) {                // ---- colmean (fp32 value) ----
        int t = x - 1536;
        int xb = t & 1, b = (t >> 1) & 7, zb = t >> 4;
        int d = xb * 256 + tid;
        const float* p = v + (size_t)b * SEQ * DMODEL + (size_t)zb * 64 * DMODEL + d;
        float s = 0.f;
#pragma unroll 8
        for (int n = 0; n < 64; ++n) s += p[(size_t)n * DMODEL];
        atomicAdd(&prof[b * DMODEL + d], s * (1.f / 1024.f));
    }
}

// -------------------------- tiny channel MLP (fp32 weights) ----------------
__global__ __launch_bounds__(256) void cmlp(const float* prof,
                                            const float* Wc1, const float* bc1,
                                            const float* Wc2, const float* bc2,
                                            u16t* cw)
{
    int b = blockIdx.x, t = threadIdx.x;
    __shared__ float pf[512];
    __shared__ float hf[256];
    pf[t]       = prof[b * 512 + t];
    pf[t + 256] = prof[b * 512 + t + 256];
    __syncthreads();
    float s = bc1[t];
    for (int k = 0; k < 512; ++k) s += pf[k] * Wc1[(size_t)k * 256 + t];
    hf[t] = fmaxf(s, 0.f);
    __syncthreads();
#pragma unroll
    for (int o = 0; o < 2; ++o) {
        int d = t + o * 256;
        float s2 = bc2[d];
        for (int k = 0; k < 256; ++k) s2 += hf[k] * Wc2[(size_t)k * 512 + d];
        cw[b * 512 + d] = f2bf(1.f / (1.f + __expf(-s2)));
    }
}

// -------------------------- WvTs[b][n][k] = WvT[n][k] * cw[b][k] -----------
__global__ __launch_bounds__(256) void scale_wv(const u16t* WvT, const u16t* cw,
                                                u16t* WvTs)
{
    int b = blockIdx.y;
    int idx = blockIdx.x * 2048 + threadIdx.x * 8;
    int k = idx & 511;
    uint4 wv = *(const uint4*)&WvT[idx];
    uint4 cu = *(const uint4*)&cw[b * 512 + k];
    const u16t* wp = (const u16t*)&wv;
    const u16t* cp = (const u16t*)&cu;
    float o[8];
#pragma unroll
    for (int q = 0; q < 8; ++q) o[q] = bf2f(wp[q]) * bf2f(cp[q]);
    *(uint4*)&WvTs[(size_t)b * 262144 + idx] = pack8(o);
}

// -------------------------- counted-vmcnt pipelined MFMA GEMM --------------
// R4 (kept): 3 LDS buffers, prologue stages 2 tiles, per K-step
// s_waitcnt vmcnt(LPT) lgkmcnt(0) (never 0 mid-loop) + raw s_barrier;
// stage(t+2) after compute(t). Loads age two compute phases.
// R15: gemm3/gemmO move from 64x64 blocks (wave 32x32, 1.0 reads/MFMA) to
// 128x64 (<3,2,2,4,2>, wave 64x32): 0.75 reads/MFMA, 2x MFMA per convoy,
// same 512-block 2/CU residency that measured best for gemm1.
template<int MINW, int WR, int WC, int WM, int NT>
__global__ __launch_bounds__(256, MINW) void gemmP(
    const u16t* A0, const u16t* A1, const u16t* A2, const u16t* A3,
    const u16t* W0, const u16t* W1, const u16t* W2, const u16t* W3,
    const float* B0, const float* B1, const float* B2, const float* B3,
    void* C0, void* C1, void* C2, void* C3,
    int N, int K, int mode,
    const u16t* VVp, u16t* VdTp,
    int tmask, int outf32, int wbmask)
{
    constexpr int BM = WR * WM * 16;
    constexpr int BN = WC * NT * 16;
    constexpr int PA = BM / 64;          // A staging rounds (256 thr x 16B)
    constexpr int PB = BN / 64;          // B staging rounds
    constexpr int LPT = PA + PB;         // gll16 per thread per K-tile

    int z = blockIdx.z;
    const u16t* A  = (z == 0) ? A0 : (z == 1) ? A1 : (z == 2) ? A2 : A3;
    const u16t* W  = (z == 0) ? W0 : (z == 1) ? W1 : (z == 2) ? W2 : W3;
    const float* Bi = (z == 0) ? B0 : (z == 1) ? B1 : (z == 2) ? B2 : B3;
    void*       C  = (z == 0) ? C0 : (z == 1) ? C1 : (z == 2) ? C2 : C3;

    int tstore = (tmask >> z) & 1;

    int tid = threadIdx.x;
    int w = tid >> 6, lane = tid & 63, quad = lane >> 4, l16 = lane & 15;
    int wr = w / WC, wc = w % WC;
    int m0 = blockIdx.x * BM, n0 = blockIdx.y * BN;
    int bb = m0 >> 10;
    if ((wbmask >> z) & 1) W += (size_t)bb * 262144;

    __shared__ __align__(16) u16t As[3][BM * 32];
    __shared__ __align__(16) u16t Bs[3][BN * 32];

    // per-thread staging sources (swizzle: slot g holds group g^(r&3))
    const u16t* srcA[PA];
#pragma unroll
    for (int p = 0; p < PA; ++p) {
        int ci = p * 256 + tid, r = ci >> 2, g = ci & 3;
        srcA[p] = A + (size_t)(m0 + r) * K + (g ^ (r & 3)) * 8;
    }
    const u16t* srcB[PB];
#pragma unroll
    for (int p = 0; p < PB; ++p) {
        int ci = p * 256 + tid, r = ci >> 2, g = ci & 3;
        srcB[p] = W + (size_t)(n0 + r) * K + (g ^ (r & 3)) * 8;
    }

    f32x4 zero = {0.f, 0.f, 0.f, 0.f};
    f32x4 acc[WM][NT];
#pragma unroll
    for (int mi = 0; mi < WM; ++mi)
#pragma unroll
        for (int ni = 0; ni < NT; ++ni) acc[mi][ni] = zero;

    auto stage = [&](int buf, int k0) {
#pragma unroll
        for (int p = 0; p < PA; ++p)
            gll16(srcA[p] + k0, &As[buf][(size_t)(p * 256 + w * 64) * 8]);
#pragma unroll
        for (int p = 0; p < PB; ++p)
            gll16(srcB[p] + k0, &Bs[buf][(size_t)(p * 256 + w * 64) * 8]);
    };
    auto compute = [&](int buf) {
        int sx = l16 & 3;
        bf8 af[WM], bfr[NT];
#pragma unroll
        for (int mi = 0; mi < WM; ++mi)
            af[mi] = *(const bf8*)&As[buf][(wr * WM * 16 + mi * 16 + l16) * 32 + ((quad ^ sx) * 8)];
#pragma unroll
        for (int ni = 0; ni < NT; ++ni)
            bfr[ni] = *(const bf8*)&Bs[buf][(wc * NT * 16 + ni * 16 + l16) * 32 + ((quad ^ sx) * 8)];
#pragma unroll
        for (int mi = 0; mi < WM; ++mi)
#pragma unroll
            for (int ni = 0; ni < NT; ++ni)
                acc[mi][ni] = __builtin_amdgcn_mfma_f32_16x16x32_bf16(af[mi], bfr[ni], acc[mi][ni], 0, 0, 0);
    };

    int nt = K >> 5;                     // >= 2 at all call sites
    stage(0, 0);
    stage(1, 32);
    for (int t = 0; t < nt; ++t) {
        if (t + 1 < nt)
            asm volatile("s_waitcnt vmcnt(%0) lgkmcnt(0)" :: "n"(LPT) : "memory");
        else
            asm volatile("s_waitcnt vmcnt(0) lgkmcnt(0)" ::: "memory");
        __builtin_amdgcn_s_barrier();
        __builtin_amdgcn_sched_barrier(0);
        compute(t % 3);
        if (t + 2 < nt) stage((t + 2) % 3, (t + 2) << 5);
    }

#pragma unroll
    for (int mi = 0; mi < WM; ++mi) {
        int grow0 = m0 + wr * WM * 16 + mi * 16 + quad * 4;
#pragma unroll
        for (int ni = 0; ni < NT; ++ni) {
            int gcol = n0 + wc * NT * 16 + ni * 16 + l16;
            float bias = Bi[gcol];
            if (mode == 2) {
                int h = gcol >> 6, dh = gcol & 63;
                int b_ = grow0 >> 10, n_ = grow0 & 1023;
                size_t tbase = (size_t)((b_ * 8 + h) * 64 + dh) * 1024 + n_;
                us4 vc = *(const us4*)&VdTp[tbase];     // Vch (transposed)
                us4 pk;
#pragma unroll
                for (int r = 0; r < 4; ++r) {
                    float s = acc[mi][ni][r] + bias;
                    float sw = 1.f / (1.f + __expf(-s));
                    float vvv = bf2f(VVp[(size_t)(grow0 + r) * DMODEL + gcol]);
                    pk[r] = f2bf(vvv * sw + bf2f(vc[r]));
                }
                *(us4*)&VdTp[tbase] = pk;               // in-place -> v_dual
            } else if (tstore) {
                int h = gcol >> 6, dh = gcol & 63;
                int b_ = grow0 >> 10, n_ = grow0 & 1023;
                us4 pk;
#pragma unroll
                for (int r = 0; r < 4; ++r) pk[r] = f2bf(acc[mi][ni][r] + bias);
                *(us4*)&((u16t*)C)[(size_t)((b_ * 8 + h) * 64 + dh) * 1024 + n_] = pk;
            } else if (outf32) {
#pragma unroll
                for (int r = 0; r < 4; ++r)
                    ((float*)C)[(size_t)(grow0 + r) * N + gcol] = acc[mi][ni][r] + bias;
            } else {
#pragma unroll
                for (int r = 0; r < 4; ++r) {
                    float v = acc[mi][ni][r] + bias;
                    if (mode == 1) v = fmaxf(v, 0.f);
                    ((u16t*)C)[(size_t)(grow0 + r) * N + gcol] = f2bf(v);
                }
            }
        }
    }
}

// -------------------------- flash attention --------------------------------
// R5-R8 (kept, measured best <41.5us): swapped QK^T -> in-register softmax;
// PV A-frag via bpermute; Q frags hoisted; prefetch-first order; v_exp_f32;
// 128q x 4 waves (2 q-groups); grid (bh,qt) -> XCD-local K/V; 128-key
// double tile (8 sync convoys). LDS 80KB = 2 blocks/CU.
__global__ __launch_bounds__(256, 2) void attn(const u16t* Q, const u16t* Km,
                                               const u16t* VdT, u16t* Oa)
{
    __shared__ __align__(16) u16t Qs[128 * 64];
    __shared__ __align__(16) u16t Ks[2][128 * 64];
    __shared__ __align__(16) u16t Vs[2][64 * 128];  // [d][key], 128-wide rows

    int bh = blockIdx.x, qt = blockIdx.y;
    int b = bh >> 3, h = bh & 7;
    int tid = threadIdx.x;
    int w = tid >> 6, lane = tid & 63, quad = lane >> 4, l16 = lane & 15;
    int l7 = l16 & 7;
    int ht = quad >> 1;
    int sA = ((quad & 1) * 32 + l16) * 4;   // bpermute byte addr, quads 0/1 or 2/3
    int sB = sA + 64;                        // +16 lanes

    const u16t* Qp = Q   + ((size_t)(b * SEQ + qt * 128)) * DMODEL + h * 64;
    const u16t* Kp = Km  + ((size_t)(b * SEQ)) * DMODEL + h * 64;
    const u16t* Vp = VdT + ((size_t)(b * 8 + h)) * 64 * SEQ;

    // stage one 128-key K/V tile (K: 128 rows x 64d; V: 64 rows x 128 keys)
    auto stageKV = [&](int buf, int it) {
#pragma unroll
        for (int p = 0; p < 4; ++p) {
            int ci = p * 256 + tid;
            int rk = ci >> 3, gk = ci & 7;            // K: 8 groups/row
            gll16(&Kp[(size_t)(it * 128 + rk) * DMODEL + ((gk ^ (rk & 7)) * 8)],
                  &Ks[buf][(size_t)(p * 256 + w * 64) * 8]);
            int rv = ci >> 4, gv = ci & 15;           // V: 16 groups/row
            gll16(&Vp[(size_t)rv * SEQ + it * 128 + ((gv ^ (rv & 15)) * 8)],
                  &Vs[buf][(size_t)(p * 256 + w * 64) * 8]);
        }
    };

    // stage Q once (128 rows, 4 rounds) + first K/V tile
#pragma unroll
    for (int p = 0; p < 4; ++p) {
        int ci = p * 256 + tid;
        int r = ci >> 3, g = ci & 7;
        int gs = (g ^ (r & 7)) * 8;
        gll16(&Qp[(size_t)r * DMODEL + gs], &Qs[(size_t)(p * 256 + w * 64) * 8]);
    }
    stageKV(0, 0);

    // Q loads (4/thread, oldest) done when vmcnt <= 8 (stageKV's 8 remain)
    asm volatile("s_waitcnt vmcnt(8)" ::: "memory");
    __builtin_amdgcn_s_barrier();
    bf8 aq[2][2];   // [q-group][ks]
#pragma unroll
    for (int qg = 0; qg < 2; ++qg)
#pragma unroll
        for (int ks = 0; ks < 2; ++ks)
            aq[qg][ks] = *(const bf8*)&Qs[(w * 32 + qg * 16 + l16) * 64 + (((ks * 4 + quad) ^ l7) * 8)];

    f32x4 zero = {0.f, 0.f, 0.f, 0.f};
    f32x4 oacc[2][4];
    float l_run[2] = {0.f, 0.f};       // denominator for q = qg*16 + l16
#pragma unroll
    for (int qg = 0; qg < 2; ++qg)
#pragma unroll
        for (int r = 0; r < 4; ++r) oacc[qg][r] = zero;

    for (int it = 0; it < 8; ++it) {
        int buf = it & 1;
        asm volatile("s_waitcnt vmcnt(0) lgkmcnt(0)" ::: "memory");
        __builtin_amdgcn_s_barrier();
        __builtin_amdgcn_sched_barrier(0);

        // prefetch next 128-key K/V first: ages through the WHOLE iteration
        if (it + 1 < 8) stageKV(buf ^ 1, it + 1);

#pragma unroll
        for (int kh = 0; kh < 2; ++kh) {   // two 64-key halves
            // K fragments once (q-group invariant)
            bf8 bk[2][4];
#pragma unroll
            for (int ks = 0; ks < 2; ++ks) {
                int sG = ((ks * 4 + quad) ^ l7) * 8;
#pragma unroll
                for (int j = 0; j < 4; ++j)
                    bk[ks][j] = *(const bf8*)&Ks[buf][(kh * 64 + j * 16 + l16) * 64 + sG];
            }
            // S^T per q-group: lane holds S[key=16j+4*quad+r][q=qg*16+l16]
            f32x4 sacc[2][4];
#pragma unroll
            for (int qg = 0; qg < 2; ++qg)
#pragma unroll
                for (int j = 0; j < 4; ++j) sacc[qg][j] = zero;
#pragma unroll
            for (int qg = 0; qg < 2; ++qg)
#pragma unroll
                for (int ks = 0; ks < 2; ++ks)
#pragma unroll
                    for (int j = 0; j < 4; ++j)
                        sacc[qg][j] = __builtin_amdgcn_mfma_f32_16x16x32_bf16(bk[ks][j], aq[qg][ks], sacc[qg][j], 0, 0, 0);

            // in-register softmax (fixed max): p = exp(s/8-4) = 2^(s*c1+c0)
            unsigned pks[2][8];
#pragma unroll
            for (int qg = 0; qg < 2; ++qg) {
                float p[4][4];
                float rsum = 0.f;
#pragma unroll
                for (int j = 0; j < 4; ++j)
#pragma unroll
                    for (int r = 0; r < 4; ++r) {
                        float xx = fmaf(sacc[qg][j][r], 0.18033688f, -5.77078016f);
                        float pe;
                        asm("v_exp_f32 %0, %1" : "=v"(pe) : "v"(xx));
                        p[j][r] = pe;
                        rsum += pe;
                    }
                rsum += __shfl_xor(rsum, 16);
                rsum += __shfl_xor(rsum, 32);
                l_run[qg] += rsum;
#pragma unroll
                for (int j = 0; j < 4; ++j)
#pragma unroll
                    for (int c = 0; c < 2; ++c) {
                        union { __bf16 hh[2]; unsigned u; } pk;
                        pk.hh[0] = (__bf16)p[j][2 * c];
                        pk.hh[1] = (__bf16)p[j][2 * c + 1];
                        pks[qg][2 * j + c] = pk.u;
                    }
            }

            // V fragments once (q-group invariant); 128-wide rows, 16-group
            bf8 bvf[2][4];
#pragma unroll
            for (int ks = 0; ks < 2; ++ks) {
#pragma unroll
                for (int j = 0; j < 4; ++j) {
                    int rv = j * 16 + l16;
                    int sG = (((kh * 8 + ks * 4 + quad) ^ (rv & 15)) * 8);
                    bvf[ks][j] = *(const bf8*)&Vs[buf][rv * 128 + sG];
                }
            }
            // O += P V: A-frag via bpermute per (qg, ks)
#pragma unroll
            for (int qg = 0; qg < 2; ++qg)
#pragma unroll
                for (int ks = 0; ks < 2; ++ks) {
                    int rA[4], rB[4];
#pragma unroll
                    for (int c = 0; c < 4; ++c) {
                        rA[c] = __builtin_amdgcn_ds_bpermute(sA, (int)pks[qg][ks * 4 + c]);
                        rB[c] = __builtin_amdgcn_ds_bpermute(sB, (int)pks[qg][ks * 4 + c]);
                    }
                    union { int d[4]; bf8 v; } apu;
                    apu.d[0] = ht ? rA[2] : rA[0];
                    apu.d[1] = ht ? rA[3] : rA[1];
                    apu.d[2] = ht ? rB[2] : rB[0];
                    apu.d[3] = ht ? rB[3] : rB[1];
#pragma unroll
                    for (int j = 0; j < 4; ++j)
                        oacc[qg][j] = __builtin_amdgcn_mfma_f32_16x16x32_bf16(apu.v, bvf[ks][j], oacc[qg][j], 0, 0, 0);
                }
        }
    }

    // epilogue: O[q][d] / l(q); l for q-group qg lives at lanes l16 == q
#pragma unroll
    for (int qg = 0; qg < 2; ++qg) {
        float lr[4];
#pragma unroll
        for (int r4 = 0; r4 < 4; ++r4)
            lr[r4] = __shfl(l_run[qg], (quad << 4) | (quad * 4 + r4));
#pragma unroll
        for (int j = 0; j < 4; ++j) {
#pragma unroll
            for (int r4 = 0; r4 < 4; ++r4) {
                int rq = qt * 128 + w * 32 + qg * 16 + quad * 4 + r4;
                float v = oacc[qg][j][r4] / lr[r4];
                Oa[((size_t)(b * SEQ + rq)) * DMODEL + h * 64 + j * 16 + l16] = f2bf(v);
            }
        }
    }
}

// ---------------------------------------------------------------------------
extern "C" void kernel_launch(void* const* d_in, const int* in_sizes, int n_in,
                              void* d_out, int out_size, void* d_ws, size_t ws_size,
                              hipStream_t stream)
{
    const float* query  = (const float*)d_in[0];
    const float* key_in = (const float*)d_in[1];
    const float* value  = (const float*)d_in[2];
    const float* Wq  = (const float*)d_in[3];  const float* bq  = (const float*)d_in[4];
    const float* Wk  = (const float*)d_in[5];  const float* bk  = (const float*)d_in[6];
    const float* Wv  = (const float*)d_in[7];  const float* bv  = (const float*)d_in[8];
    const float* Wo  = (const float*)d_in[9];  const float* bo  = (const float*)d_in[10];
    const float* Ws1 = (const float*)d_in[11]; const float* bs1 = (const float*)d_in[12];
    const float* Ws2 = (const float*)d_in[13]; const float* bs2 = (const float*)d_in[14];
    const float* Wc1 = (const float*)d_in[15]; const float* bc1 = (const float*)d_in[16];
    const float* Wc2 = (const float*)d_in[17]; const float* bc2 = (const float*)d_in[18];
    float* out = (float*)d_out;

    // workspace map (u16 units), high-water 32,780,288 u16 = 65.56 MB
    u16t* ws = (u16t*)d_ws;
    u16t* WqT  = ws + 0;                   // [0, 262144)
    u16t* WkT  = ws + 262144;              // [262144, 524288)
    u16t* WvT  = ws + 524288;              // [524288, 786432)
    u16t* WoT  = ws + 786432;              // [786432, 1048576)
    u16t* Ws1T = ws + 1048576;             // [1048576, 1179648)
    u16t* Ws2T = ws + 1179648;             // [1179648, 1310720)
    u16t* WvTs = ws + 1310720;             // [8][512][512]   [1310720, 3407872)
    u16t* Vi   = ws + 3407872;             // bf16 value      [3407872, 7602176)  (H1 later)
    u16t* Qm   = ws + 7602176;             // [7602176, 11796480)
    u16t* Kmm  = ws + 11796480;            // [11796480, 15990784)
    u16t* VV   = ws + 15990784;            // [15990784, 20185088)  (Oa later)
    u16t* VdT  = ws + 20185088;            // [20185088, 24379392)
    u16t* cw   = ws + 24379392;            // [24379392, 24383488)
    float* prof = (float*)(ws + 24383488); // 8192 u16 [24383488, 24391680)
    u16t* Qbf  = ws + 24391680;            // bf16 query  [24391680, 28585984)
    u16t* Kbf  = ws + 28585984;            // bf16 key    [28585984, 32780288)
    u16t* H1 = Vi;                         // Vi dead after gemm1
    u16t* Oa = VV;                         // VV dead after gemm3

    const size_t NEED_BYTES = 32780288ull * 2ull;
    if (ws_size < NEED_BYTES) {
        fill_sentinel<<<(out_size + 255) / 256, 256, 0, stream>>>(out, out_size);
        return;
    }

    hipMemsetAsync((void*)prof, 0, NBATCH * DMODEL * sizeof(float), stream);

    // fused prologue: cvt3 + transpose6 + colmean in one launch
    prep<<<dim3(2048, 4), 256, 0, stream>>>(
        query, key_in, value, Qbf, Kbf, Vi,
        Wq, Wk, Wv, Wo, Ws1, Ws2,
        WqT, WkT, WvT, WoT, Ws1T, Ws2T,
        prof);
    cmlp<<<8, 256, 0, stream>>>(prof, Wc1, bc1, Wc2, bc2, cw);
    scale_wv<<<dim3(128, 8), 256, 0, stream>>>(WvT, cw, WvTs);

    // 4 parallel big GEMMs: Q, K, VV, Vch (z=3: per-batch scaled Wv, tstore)
    // 128x256 tiles, counted-vmcnt pipeline; 512 blocks = exactly 2/CU
    gemmP<2, 2, 2, 4, 8><<<dim3(64, 2, 4), 256, 0, stream>>>(
        Qbf, Kbf, Vi, Vi,
        WqT, WkT, WvT, WvTs,
        bq, bk, bv, bv,
        Qm, Kmm, VV, VdT,
        512, 512, 0, nullptr, VdT,
        /*tmask*/0x8, /*outf32*/0, /*wbmask*/0x8);

    // spatial gate MLP: H1 = relu(VV @ Ws1 + bs1) — 64x64 tiles (N=256 caps
    // the grid for wider tiles; keep measured config)
    gemmP<4, 2, 2, 2, 2><<<dim3(128, 4, 1), 256, 0, stream>>>(
        VV, VV, VV, VV, Ws1T, Ws1T, Ws1T, Ws1T, bs1, bs1, bs1, bs1,
        H1, H1, H1, H1, 256, 512, 1, nullptr, nullptr, 0, 0, 0);

    // sw = sigmoid(H1 @ Ws2 + bs2); VdT = VV*sw + VdT (in place, transposed)
    // 128x64 tiles: 512 blocks = 2/CU, 0.75 reads/MFMA
    gemmP<3, 2, 2, 4, 2><<<dim3(64, 8, 1), 256, 0, stream>>>(
        H1, H1, H1, H1, Ws2T, Ws2T, Ws2T, Ws2T, bs2, bs2, bs2, bs2,
        Qm, Qm, Qm, Qm,   // dummy C (unused in mode 2)
        512, 256, 2, VV, VdT, 0, 0, 0);

    // attention: 128q x 128k-iter tiles; grid (bh, qt) -> bh%8 picks XCD,
    // all q-tiles of one (b,h) share an XCD's L2 copy of K/V
    attn<<<dim3(64, 8), 256, 0, stream>>>(Qm, Kmm, VdT, Oa);

    // final projection -> fp32 d_out (128x64 tiles: 512 blocks = 2/CU)
    gemmP<3, 2, 2, 4, 2><<<dim3(64, 8, 1), 256, 0, stream>>>(
        Oa, Oa, Oa, Oa, WoT, WoT, WoT, WoT, bo, bo, bo, bo,
        out, out, out, out, 512, 512, 0, nullptr, nullptr,
        0, /*outf32*/1, 0);
}

// Round 16
// 256.091 us; speedup vs baseline: 1.0449x; 1.0449x over previous
//
#include <hip/hip_runtime.h>

typedef unsigned short u16t;
typedef __bf16  bf8   __attribute__((ext_vector_type(8)));
typedef float   f32x4 __attribute__((ext_vector_type(4)));
typedef unsigned short us4 __attribute__((ext_vector_type(4)));

#define DEV __device__ __forceinline__

DEV float bf2f(u16t u) { union { unsigned u; float f; } x; x.u = ((unsigned)u) << 16; return x.f; }
DEV u16t  f2bf(float f) {
    union { float f; unsigned u; } x; x.f = f;
    unsigned r = x.u + 0x7FFFu + ((x.u >> 16) & 1u);
    return (u16t)(r >> 16);
}
DEV uint4 pack8(const float* v) {
    uint4 r;
    r.x = (unsigned)f2bf(v[0]) | ((unsigned)f2bf(v[1]) << 16);
    r.y = (unsigned)f2bf(v[2]) | ((unsigned)f2bf(v[3]) << 16);
    r.z = (unsigned)f2bf(v[4]) | ((unsigned)f2bf(v[5]) << 16);
    r.w = (unsigned)f2bf(v[6]) | ((unsigned)f2bf(v[7]) << 16);
    return r;
}
// async global->LDS, 16B per lane; lds dest = wave-uniform base + lane*16
DEV void gll16(const void* g, void* l) {
    __builtin_amdgcn_global_load_lds(
        (const __attribute__((address_space(1))) unsigned*)g,
        (__attribute__((address_space(3))) unsigned*)l, 16, 0, 0);
}

#define DMODEL 512
#define SEQ    1024
#define NBATCH 8

// -------------------------- ws-too-small sentinel --------------------------
__global__ __launch_bounds__(256) void fill_sentinel(float* out, int n)
{
    int i = blockIdx.x * 256 + threadIdx.x;
    if (i < n) out[i] = 100.f;
}

// -------------------------- fused prologue ---------------------------------
// R13 (kept — saved ~9us): cvt3 + transpose6 + colmean in ONE launch; the
// transpose/colmean work runs concurrently under cvt3's stream.
// grid (2048, 4): y<3 = cvt q/k/v; y==3: x<1536 transpose6, x<1792 colmean.
__global__ __launch_bounds__(256) void prep(
    const float* q, const float* k, const float* v,
    u16t* Qb, u16t* Kb, u16t* Vb,
    const float* s0, const float* s1, const float* s2, const float* s3,
    const float* s4, const float* s5,
    u16t* d0, u16t* d1, u16t* d2, u16t* d3, u16t* d4, u16t* d5,
    float* prof)
{
    __shared__ u16t tile[32][33];
    int y = blockIdx.y, tid = threadIdx.x;
    if (y < 3) {
        const float* s = (y == 0) ? q : (y == 1) ? k : v;
        u16t*        d = (y == 0) ? Qb : (y == 1) ? Kb : Vb;
        size_t i = ((size_t)blockIdx.x * 256 + tid) * 8;
        float4 a = *(const float4*)(s + i), b = *(const float4*)(s + i + 4);
        float o[8] = {a.x, a.y, a.z, a.w, b.x, b.y, b.z, b.w};
        *(uint4*)&d[i] = pack8(o);
        return;
    }
    int x = blockIdx.x;
    if (x < 1536) {                       // ---- transpose6 ----
        int z = x >> 8, rem = x & 255;
        int bx = rem & 15, by = rem >> 4;
        const float* S; u16t* D; int R, C;
        switch (z) {
            case 0: S = s0; D = d0; R = 512; C = 512; break;
            case 1: S = s1; D = d1; R = 512; C = 512; break;
            case 2: S = s2; D = d2; R = 512; C = 512; break;
            case 3: S = s3; D = d3; R = 512; C = 512; break;
            case 4: S = s4; D = d4; R = 512; C = 256; break;  // Ws1 [512,256]
            default:S = s5; D = d5; R = 256; C = 512; break;  // Ws2 [256,512]
        }
        int c0 = bx * 32, r0 = by * 32;
        if (c0 >= C || r0 >= R) return;
        int tx = tid & 31, ty = tid >> 5;   // 32 x 8
#pragma unroll
        for (int p = 0; p < 4; ++p) {
            int r = ty + p * 8;
            tile[r][tx] = f2bf(S[(size_t)(r0 + r) * C + c0 + tx]);
        }
        __syncthreads();
#pragma unroll
        for (int p = 0; p < 4; ++p) {
            int r = ty + p * 8;
            D[(size_t)(c0 + r) * R + r0 + tx] = tile[tx][r];
        }
    } else if (x < 1792) {                // ---- colmean (fp32 value) ----
        int t = x - 1536;
        int xb = t & 1, b = (t >> 1) & 7, zb = t >> 4;
        int d = xb * 256 + tid;
        const float* p = v + (size_t)b * SEQ * DMODEL + (size_t)zb * 64 * DMODEL + d;
        float s = 0.f;
#pragma unroll 8
        for (int n = 0; n < 64; ++n) s += p[(size_t)n * DMODEL];
        atomicAdd(&prof[b * DMODEL + d], s * (1.f / 1024.f));
    }
}

// -------------------------- tiny channel MLP (fp32 weights) ----------------
__global__ __launch_bounds__(256) void cmlp(const float* prof,
                                            const float* Wc1, const float* bc1,
                                            const float* Wc2, const float* bc2,
                                            u16t* cw)
{
    int b = blockIdx.x, t = threadIdx.x;
    __shared__ float pf[512];
    __shared__ float hf[256];
    pf[t]       = prof[b * 512 + t];
    pf[t + 256] = prof[b * 512 + t + 256];
    __syncthreads();
    float s = bc1[t];
    for (int k = 0; k < 512; ++k) s += pf[k] * Wc1[(size_t)k * 256 + t];
    hf[t] = fmaxf(s, 0.f);
    __syncthreads();
#pragma unroll
    for (int o = 0; o < 2; ++o) {
        int d = t + o * 256;
        float s2 = bc2[d];
        for (int k = 0; k < 256; ++k) s2 += hf[k] * Wc2[(size_t)k * 512 + d];
        cw[b * 512 + d] = f2bf(1.f / (1.f + __expf(-s2)));
    }
}

// -------------------------- WvTs[b][n][k] = WvT[n][k] * cw[b][k] -----------
__global__ __launch_bounds__(256) void scale_wv(const u16t* WvT, const u16t* cw,
                                                u16t* WvTs)
{
    int b = blockIdx.y;
    int idx = blockIdx.x * 2048 + threadIdx.x * 8;
    int k = idx & 511;
    uint4 wv = *(const uint4*)&WvT[idx];
    uint4 cu = *(const uint4*)&cw[b * 512 + k];
    const u16t* wp = (const u16t*)&wv;
    const u16t* cp = (const u16t*)&cu;
    float o[8];
#pragma unroll
    for (int q = 0; q < 8; ++q) o[q] = bf2f(wp[q]) * bf2f(cp[q]);
    *(uint4*)&WvTs[(size_t)b * 262144 + idx] = pack8(o);
}

// -------------------------- counted-vmcnt pipelined MFMA GEMM --------------
// R4 (kept): 3 LDS buffers, prologue stages 2 tiles, per K-step
// s_waitcnt vmcnt(LPT) lgkmcnt(0) (never 0 mid-loop) + raw s_barrier;
// stage(t+2) after compute(t). Loads age two compute phases.
// R16: reverted to R14's exact measured-best tiles (both R13's 128x128 and
// R15's 128x64 retiles regressed — in this convoy-bound regime, per-step
// amortization + in-flight bytes dominate the reads/MFMA ratio; the R14
// configs are local optima).
template<int MINW, int WR, int WC, int WM, int NT>
__global__ __launch_bounds__(256, MINW) void gemmP(
    const u16t* A0, const u16t* A1, const u16t* A2, const u16t* A3,
    const u16t* W0, const u16t* W1, const u16t* W2, const u16t* W3,
    const float* B0, const float* B1, const float* B2, const float* B3,
    void* C0, void* C1, void* C2, void* C3,
    int N, int K, int mode,
    const u16t* VVp, u16t* VdTp,
    int tmask, int outf32, int wbmask)
{
    constexpr int BM = WR * WM * 16;
    constexpr int BN = WC * NT * 16;
    constexpr int PA = BM / 64;          // A staging rounds (256 thr x 16B)
    constexpr int PB = BN / 64;          // B staging rounds
    constexpr int LPT = PA + PB;         // gll16 per thread per K-tile

    int z = blockIdx.z;
    const u16t* A  = (z == 0) ? A0 : (z == 1) ? A1 : (z == 2) ? A2 : A3;
    const u16t* W  = (z == 0) ? W0 : (z == 1) ? W1 : (z == 2) ? W2 : W3;
    const float* Bi = (z == 0) ? B0 : (z == 1) ? B1 : (z == 2) ? B2 : B3;
    void*       C  = (z == 0) ? C0 : (z == 1) ? C1 : (z == 2) ? C2 : C3;

    int tstore = (tmask >> z) & 1;

    int tid = threadIdx.x;
    int w = tid >> 6, lane = tid & 63, quad = lane >> 4, l16 = lane & 15;
    int wr = w / WC, wc = w % WC;
    int m0 = blockIdx.x * BM, n0 = blockIdx.y * BN;
    int bb = m0 >> 10;
    if ((wbmask >> z) & 1) W += (size_t)bb * 262144;

    __shared__ __align__(16) u16t As[3][BM * 32];
    __shared__ __align__(16) u16t Bs[3][BN * 32];

    // per-thread staging sources (swizzle: slot g holds group g^(r&3))
    const u16t* srcA[PA];
#pragma unroll
    for (int p = 0; p < PA; ++p) {
        int ci = p * 256 + tid, r = ci >> 2, g = ci & 3;
        srcA[p] = A + (size_t)(m0 + r) * K + (g ^ (r & 3)) * 8;
    }
    const u16t* srcB[PB];
#pragma unroll
    for (int p = 0; p < PB; ++p) {
        int ci = p * 256 + tid, r = ci >> 2, g = ci & 3;
        srcB[p] = W + (size_t)(n0 + r) * K + (g ^ (r & 3)) * 8;
    }

    f32x4 zero = {0.f, 0.f, 0.f, 0.f};
    f32x4 acc[WM][NT];
#pragma unroll
    for (int mi = 0; mi < WM; ++mi)
#pragma unroll
        for (int ni = 0; ni < NT; ++ni) acc[mi][ni] = zero;

    auto stage = [&](int buf, int k0) {
#pragma unroll
        for (int p = 0; p < PA; ++p)
            gll16(srcA[p] + k0, &As[buf][(size_t)(p * 256 + w * 64) * 8]);
#pragma unroll
        for (int p = 0; p < PB; ++p)
            gll16(srcB[p] + k0, &Bs[buf][(size_t)(p * 256 + w * 64) * 8]);
    };
    auto compute = [&](int buf) {
        int sx = l16 & 3;
        bf8 af[WM], bfr[NT];
#pragma unroll
        for (int mi = 0; mi < WM; ++mi)
            af[mi] = *(const bf8*)&As[buf][(wr * WM * 16 + mi * 16 + l16) * 32 + ((quad ^ sx) * 8)];
#pragma unroll
        for (int ni = 0; ni < NT; ++ni)
            bfr[ni] = *(const bf8*)&Bs[buf][(wc * NT * 16 + ni * 16 + l16) * 32 + ((quad ^ sx) * 8)];
#pragma unroll
        for (int mi = 0; mi < WM; ++mi)
#pragma unroll
            for (int ni = 0; ni < NT; ++ni)
                acc[mi][ni] = __builtin_amdgcn_mfma_f32_16x16x32_bf16(af[mi], bfr[ni], acc[mi][ni], 0, 0, 0);
    };

    int nt = K >> 5;                     // >= 2 at all call sites
    stage(0, 0);
    stage(1, 32);
    for (int t = 0; t < nt; ++t) {
        if (t + 1 < nt)
            asm volatile("s_waitcnt vmcnt(%0) lgkmcnt(0)" :: "n"(LPT) : "memory");
        else
            asm volatile("s_waitcnt vmcnt(0) lgkmcnt(0)" ::: "memory");
        __builtin_amdgcn_s_barrier();
        __builtin_amdgcn_sched_barrier(0);
        compute(t % 3);
        if (t + 2 < nt) stage((t + 2) % 3, (t + 2) << 5);
    }

#pragma unroll
    for (int mi = 0; mi < WM; ++mi) {
        int grow0 = m0 + wr * WM * 16 + mi * 16 + quad * 4;
#pragma unroll
        for (int ni = 0; ni < NT; ++ni) {
            int gcol = n0 + wc * NT * 16 + ni * 16 + l16;
            float bias = Bi[gcol];
            if (mode == 2) {
                int h = gcol >> 6, dh = gcol & 63;
                int b_ = grow0 >> 10, n_ = grow0 & 1023;
                size_t tbase = (size_t)((b_ * 8 + h) * 64 + dh) * 1024 + n_;
                us4 vc = *(const us4*)&VdTp[tbase];     // Vch (transposed)
                us4 pk;
#pragma unroll
                for (int r = 0; r < 4; ++r) {
                    float s = acc[mi][ni][r] + bias;
                    float sw = 1.f / (1.f + __expf(-s));
                    float vvv = bf2f(VVp[(size_t)(grow0 + r) * DMODEL + gcol]);
                    pk[r] = f2bf(vvv * sw + bf2f(vc[r]));
                }
                *(us4*)&VdTp[tbase] = pk;               // in-place -> v_dual
            } else if (tstore) {
                int h = gcol >> 6, dh = gcol & 63;
                int b_ = grow0 >> 10, n_ = grow0 & 1023;
                us4 pk;
#pragma unroll
                for (int r = 0; r < 4; ++r) pk[r] = f2bf(acc[mi][ni][r] + bias);
                *(us4*)&((u16t*)C)[(size_t)((b_ * 8 + h) * 64 + dh) * 1024 + n_] = pk;
            } else if (outf32) {
#pragma unroll
                for (int r = 0; r < 4; ++r)
                    ((float*)C)[(size_t)(grow0 + r) * N + gcol] = acc[mi][ni][r] + bias;
            } else {
#pragma unroll
                for (int r = 0; r < 4; ++r) {
                    float v = acc[mi][ni][r] + bias;
                    if (mode == 1) v = fmaxf(v, 0.f);
                    ((u16t*)C)[(size_t)(grow0 + r) * N + gcol] = f2bf(v);
                }
            }
        }
    }
}

// -------------------------- flash attention --------------------------------
// R5-R8 (kept, measured best <41.5us): swapped QK^T -> in-register softmax;
// PV A-frag via bpermute; Q frags hoisted; prefetch-first order; v_exp_f32;
// 128q x 4 waves (2 q-groups); grid (bh,qt) -> XCD-local K/V; 128-key
// double tile (8 sync convoys). LDS 80KB = 2 blocks/CU.
__global__ __launch_bounds__(256, 2) void attn(const u16t* Q, const u16t* Km,
                                               const u16t* VdT, u16t* Oa)
{
    __shared__ __align__(16) u16t Qs[128 * 64];
    __shared__ __align__(16) u16t Ks[2][128 * 64];
    __shared__ __align__(16) u16t Vs[2][64 * 128];  // [d][key], 128-wide rows

    int bh = blockIdx.x, qt = blockIdx.y;
    int b = bh >> 3, h = bh & 7;
    int tid = threadIdx.x;
    int w = tid >> 6, lane = tid & 63, quad = lane >> 4, l16 = lane & 15;
    int l7 = l16 & 7;
    int ht = quad >> 1;
    int sA = ((quad & 1) * 32 + l16) * 4;   // bpermute byte addr, quads 0/1 or 2/3
    int sB = sA + 64;                        // +16 lanes

    const u16t* Qp = Q   + ((size_t)(b * SEQ + qt * 128)) * DMODEL + h * 64;
    const u16t* Kp = Km  + ((size_t)(b * SEQ)) * DMODEL + h * 64;
    const u16t* Vp = VdT + ((size_t)(b * 8 + h)) * 64 * SEQ;

    // stage one 128-key K/V tile (K: 128 rows x 64d; V: 64 rows x 128 keys)
    auto stageKV = [&](int buf, int it) {
#pragma unroll
        for (int p = 0; p < 4; ++p) {
            int ci = p * 256 + tid;
            int rk = ci >> 3, gk = ci & 7;            // K: 8 groups/row
            gll16(&Kp[(size_t)(it * 128 + rk) * DMODEL + ((gk ^ (rk & 7)) * 8)],
                  &Ks[buf][(size_t)(p * 256 + w * 64) * 8]);
            int rv = ci >> 4, gv = ci & 15;           // V: 16 groups/row
            gll16(&Vp[(size_t)rv * SEQ + it * 128 + ((gv ^ (rv & 15)) * 8)],
                  &Vs[buf][(size_t)(p * 256 + w * 64) * 8]);
        }
    };

    // stage Q once (128 rows, 4 rounds) + first K/V tile
#pragma unroll
    for (int p = 0; p < 4; ++p) {
        int ci = p * 256 + tid;
        int r = ci >> 3, g = ci & 7;
        int gs = (g ^ (r & 7)) * 8;
        gll16(&Qp[(size_t)r * DMODEL + gs], &Qs[(size_t)(p * 256 + w * 64) * 8]);
    }
    stageKV(0, 0);

    // Q loads (4/thread, oldest) done when vmcnt <= 8 (stageKV's 8 remain)
    asm volatile("s_waitcnt vmcnt(8)" ::: "memory");
    __builtin_amdgcn_s_barrier();
    bf8 aq[2][2];   // [q-group][ks]
#pragma unroll
    for (int qg = 0; qg < 2; ++qg)
#pragma unroll
        for (int ks = 0; ks < 2; ++ks)
            aq[qg][ks] = *(const bf8*)&Qs[(w * 32 + qg * 16 + l16) * 64 + (((ks * 4 + quad) ^ l7) * 8)];

    f32x4 zero = {0.f, 0.f, 0.f, 0.f};
    f32x4 oacc[2][4];
    float l_run[2] = {0.f, 0.f};       // denominator for q = qg*16 + l16
#pragma unroll
    for (int qg = 0; qg < 2; ++qg)
#pragma unroll
        for (int r = 0; r < 4; ++r) oacc[qg][r] = zero;

    for (int it = 0; it < 8; ++it) {
        int buf = it & 1;
        asm volatile("s_waitcnt vmcnt(0) lgkmcnt(0)" ::: "memory");
        __builtin_amdgcn_s_barrier();
        __builtin_amdgcn_sched_barrier(0);

        // prefetch next 128-key K/V first: ages through the WHOLE iteration
        if (it + 1 < 8) stageKV(buf ^ 1, it + 1);

#pragma unroll
        for (int kh = 0; kh < 2; ++kh) {   // two 64-key halves
            // K fragments once (q-group invariant)
            bf8 bk[2][4];
#pragma unroll
            for (int ks = 0; ks < 2; ++ks) {
                int sG = ((ks * 4 + quad) ^ l7) * 8;
#pragma unroll
                for (int j = 0; j < 4; ++j)
                    bk[ks][j] = *(const bf8*)&Ks[buf][(kh * 64 + j * 16 + l16) * 64 + sG];
            }
            // S^T per q-group: lane holds S[key=16j+4*quad+r][q=qg*16+l16]
            f32x4 sacc[2][4];
#pragma unroll
            for (int qg = 0; qg < 2; ++qg)
#pragma unroll
                for (int j = 0; j < 4; ++j) sacc[qg][j] = zero;
#pragma unroll
            for (int qg = 0; qg < 2; ++qg)
#pragma unroll
                for (int ks = 0; ks < 2; ++ks)
#pragma unroll
                    for (int j = 0; j < 4; ++j)
                        sacc[qg][j] = __builtin_amdgcn_mfma_f32_16x16x32_bf16(bk[ks][j], aq[qg][ks], sacc[qg][j], 0, 0, 0);

            // in-register softmax (fixed max): p = exp(s/8-4) = 2^(s*c1+c0)
            unsigned pks[2][8];
#pragma unroll
            for (int qg = 0; qg < 2; ++qg) {
                float p[4][4];
                float rsum = 0.f;
#pragma unroll
                for (int j = 0; j < 4; ++j)
#pragma unroll
                    for (int r = 0; r < 4; ++r) {
                        float xx = fmaf(sacc[qg][j][r], 0.18033688f, -5.77078016f);
                        float pe;
                        asm("v_exp_f32 %0, %1" : "=v"(pe) : "v"(xx));
                        p[j][r] = pe;
                        rsum += pe;
                    }
                rsum += __shfl_xor(rsum, 16);
                rsum += __shfl_xor(rsum, 32);
                l_run[qg] += rsum;
#pragma unroll
                for (int j = 0; j < 4; ++j)
#pragma unroll
                    for (int c = 0; c < 2; ++c) {
                        union { __bf16 hh[2]; unsigned u; } pk;
                        pk.hh[0] = (__bf16)p[j][2 * c];
                        pk.hh[1] = (__bf16)p[j][2 * c + 1];
                        pks[qg][2 * j + c] = pk.u;
                    }
            }

            // V fragments once (q-group invariant); 128-wide rows, 16-group
            bf8 bvf[2][4];
#pragma unroll
            for (int ks = 0; ks < 2; ++ks) {
#pragma unroll
                for (int j = 0; j < 4; ++j) {
                    int rv = j * 16 + l16;
                    int sG = (((kh * 8 + ks * 4 + quad) ^ (rv & 15)) * 8);
                    bvf[ks][j] = *(const bf8*)&Vs[buf][rv * 128 + sG];
                }
            }
            // O += P V: A-frag via bpermute per (qg, ks)
#pragma unroll
            for (int qg = 0; qg < 2; ++qg)
#pragma unroll
                for (int ks = 0; ks < 2; ++ks) {
                    int rA[4], rB[4];
#pragma unroll
                    for (int c = 0; c < 4; ++c) {
                        rA[c] = __builtin_amdgcn_ds_bpermute(sA, (int)pks[qg][ks * 4 + c]);
                        rB[c] = __builtin_amdgcn_ds_bpermute(sB, (int)pks[qg][ks * 4 + c]);
                    }
                    union { int d[4]; bf8 v; } apu;
                    apu.d[0] = ht ? rA[2] : rA[0];
                    apu.d[1] = ht ? rA[3] : rA[1];
                    apu.d[2] = ht ? rB[2] : rB[0];
                    apu.d[3] = ht ? rB[3] : rB[1];
#pragma unroll
                    for (int j = 0; j < 4; ++j)
                        oacc[qg][j] = __builtin_amdgcn_mfma_f32_16x16x32_bf16(apu.v, bvf[ks][j], oacc[qg][j], 0, 0, 0);
                }
        }
    }

    // epilogue: O[q][d] / l(q); l for q-group qg lives at lanes l16 == q
#pragma unroll
    for (int qg = 0; qg < 2; ++qg) {
        float lr[4];
#pragma unroll
        for (int r4 = 0; r4 < 4; ++r4)
            lr[r4] = __shfl(l_run[qg], (quad << 4) | (quad * 4 + r4));
#pragma unroll
        for (int j = 0; j < 4; ++j) {
#pragma unroll
            for (int r4 = 0; r4 < 4; ++r4) {
                int rq = qt * 128 + w * 32 + qg * 16 + quad * 4 + r4;
                float v = oacc[qg][j][r4] / lr[r4];
                Oa[((size_t)(b * SEQ + rq)) * DMODEL + h * 64 + j * 16 + l16] = f2bf(v);
            }
        }
    }
}

// ---------------------------------------------------------------------------
extern "C" void kernel_launch(void* const* d_in, const int* in_sizes, int n_in,
                              void* d_out, int out_size, void* d_ws, size_t ws_size,
                              hipStream_t stream)
{
    const float* query  = (const float*)d_in[0];
    const float* key_in = (const float*)d_in[1];
    const float* value  = (const float*)d_in[2];
    const float* Wq  = (const float*)d_in[3];  const float* bq  = (const float*)d_in[4];
    const float* Wk  = (const float*)d_in[5];  const float* bk  = (const float*)d_in[6];
    const float* Wv  = (const float*)d_in[7];  const float* bv  = (const float*)d_in[8];
    const float* Wo  = (const float*)d_in[9];  const float* bo  = (const float*)d_in[10];
    const float* Ws1 = (const float*)d_in[11]; const float* bs1 = (const float*)d_in[12];
    const float* Ws2 = (const float*)d_in[13]; const float* bs2 = (const float*)d_in[14];
    const float* Wc1 = (const float*)d_in[15]; const float* bc1 = (const float*)d_in[16];
    const float* Wc2 = (const float*)d_in[17]; const float* bc2 = (const float*)d_in[18];
    float* out = (float*)d_out;

    // workspace map (u16 units), high-water 32,780,288 u16 = 65.56 MB
    u16t* ws = (u16t*)d_ws;
    u16t* WqT  = ws + 0;                   // [0, 262144)
    u16t* WkT  = ws + 262144;              // [262144, 524288)
    u16t* WvT  = ws + 524288;              // [524288, 786432)
    u16t* WoT  = ws + 786432;              // [786432, 1048576)
    u16t* Ws1T = ws + 1048576;             // [1048576, 1179648)
    u16t* Ws2T = ws + 1179648;             // [1179648, 1310720)
    u16t* WvTs = ws + 1310720;             // [8][512][512]   [1310720, 3407872)
    u16t* Vi   = ws + 3407872;             // bf16 value      [3407872, 7602176)  (H1 later)
    u16t* Qm   = ws + 7602176;             // [7602176, 11796480)
    u16t* Kmm  = ws + 11796480;            // [11796480, 15990784)
    u16t* VV   = ws + 15990784;            // [15990784, 20185088)  (Oa later)
    u16t* VdT  = ws + 20185088;            // [20185088, 24379392)
    u16t* cw   = ws + 24379392;            // [24379392, 24383488)
    float* prof = (float*)(ws + 24383488); // 8192 u16 [24383488, 24391680)
    u16t* Qbf  = ws + 24391680;            // bf16 query  [24391680, 28585984)
    u16t* Kbf  = ws + 28585984;            // bf16 key    [28585984, 32780288)
    u16t* H1 = Vi;                         // Vi dead after gemm1
    u16t* Oa = VV;                         // VV dead after gemm3

    const size_t NEED_BYTES = 32780288ull * 2ull;
    if (ws_size < NEED_BYTES) {
        fill_sentinel<<<(out_size + 255) / 256, 256, 0, stream>>>(out, out_size);
        return;
    }

    hipMemsetAsync((void*)prof, 0, NBATCH * DMODEL * sizeof(float), stream);

    // fused prologue: cvt3 + transpose6 + colmean in one launch
    prep<<<dim3(2048, 4), 256, 0, stream>>>(
        query, key_in, value, Qbf, Kbf, Vi,
        Wq, Wk, Wv, Wo, Ws1, Ws2,
        WqT, WkT, WvT, WoT, Ws1T, Ws2T,
        prof);
    cmlp<<<8, 256, 0, stream>>>(prof, Wc1, bc1, Wc2, bc2, cw);
    scale_wv<<<dim3(128, 8), 256, 0, stream>>>(WvT, cw, WvTs);

    // 4 parallel big GEMMs: Q, K, VV, Vch (z=3: per-batch scaled Wv, tstore)
    // 128x256 tiles, counted-vmcnt pipeline; 512 blocks = exactly 2/CU
    gemmP<2, 2, 2, 4, 8><<<dim3(64, 2, 4), 256, 0, stream>>>(
        Qbf, Kbf, Vi, Vi,
        WqT, WkT, WvT, WvTs,
        bq, bk, bv, bv,
        Qm, Kmm, VV, VdT,
        512, 512, 0, nullptr, VdT,
        /*tmask*/0x8, /*outf32*/0, /*wbmask*/0x8);

    // spatial gate MLP: H1 = relu(VV @ Ws1 + bs1) — 64x64 tiles
    gemmP<4, 2, 2, 2, 2><<<dim3(128, 4, 1), 256, 0, stream>>>(
        VV, VV, VV, VV, Ws1T, Ws1T, Ws1T, Ws1T, bs1, bs1, bs1, bs1,
        H1, H1, H1, H1, 256, 512, 1, nullptr, nullptr, 0, 0, 0);

    // sw = sigmoid(H1 @ Ws2 + bs2); VdT = VV*sw + VdT (in place, transposed)
    gemmP<4, 2, 2, 2, 2><<<dim3(128, 8, 1), 256, 0, stream>>>(
        H1, H1, H1, H1, Ws2T, Ws2T, Ws2T, Ws2T, bs2, bs2, bs2, bs2,
        Qm, Qm, Qm, Qm,   // dummy C (unused in mode 2)
        512, 256, 2, VV, VdT, 0, 0, 0);

    // attention: 128q x 128k-iter tiles; grid (bh, qt) -> bh%8 picks XCD,
    // all q-tiles of one (b,h) share an XCD's L2 copy of K/V
    attn<<<dim3(64, 8), 256, 0, stream>>>(Qm, Kmm, VdT, Oa);

    // final projection -> fp32 d_out (64x64 tiles)
    gemmP<4, 2, 2, 2, 2><<<dim3(128, 8, 1), 256, 0, stream>>>(
        Oa, Oa, Oa, Oa, WoT, WoT, WoT, WoT, bo, bo, bo, bo,
        out, out, out, out, 512, 512, 0, nullptr, nullptr,
        0, /*outf32*/1, 0);
}